// Round 9
// baseline (339.271 us; speedup 1.0000x reference)
//
#include <hip/hip_runtime.h>
#include <hip/hip_bf16.h>
#include <math.h>

typedef unsigned short u16;
typedef unsigned int u32;
typedef __attribute__((ext_vector_type(8))) short short8;
typedef __attribute__((ext_vector_type(4))) float f32x4;

#define L_SEQ 4096
#define N_TOK 16384
#define D_MODEL 1024
#define R_DIM 16
#define PLU 120
#define G_DIM 256
#define K_CAT 1536  // 6 deltas * 256
#define K_GATE 2048

typedef __attribute__((address_space(1))) const void* as1cvp;
typedef __attribute__((address_space(3))) void* as3vp;
// async global->LDS, 16B per lane; LDS dest is wave-uniform base + lane*16
#define GLD16(g, l) \
  __builtin_amdgcn_global_load_lds((as1cvp)(g), (as3vp)(l), 16, 0, 0)

#define CFENCE asm volatile("" ::: "memory")
#define BARB                        \
  {                                 \
    CFENCE;                         \
    __builtin_amdgcn_s_barrier();   \
    CFENCE;                         \
  }
#define VM0 asm volatile("s_waitcnt vmcnt(0)" ::: "memory")

__device__ __forceinline__ u16 f2bf(float f) {
  u32 x = __float_as_uint(f);
  u32 lsb = (x >> 16) & 1u;
  x += 0x7fffu + lsb;
  return (u16)(x >> 16);
}
__device__ __forceinline__ float bf2f(u16 u) {
  return __uint_as_float(((u32)u) << 16);
}
__device__ __forceinline__ u32 pack2(float a, float b) {
  return (u32)f2bf(a) | ((u32)f2bf(b) << 16);
}

// exact-GELU via A&S 7.1.26 erf (|eps|<=1.5e-7): ~16 VALU vs libm erff ~35.
__device__ __forceinline__ float gelu_erf(float x) {
  const float y = x * 0.70710678118654752f;
  const float a = fabsf(y);
  const float t = __builtin_amdgcn_rcpf(fmaf(0.3275911f, a, 1.0f));
  float poly = fmaf(1.061405429f, t, -1.453152027f);
  poly = fmaf(poly, t, 1.421413741f);
  poly = fmaf(poly, t, -0.284496736f);
  poly = fmaf(poly, t, 0.254829592f);
  poly *= t;
  const float e = __builtin_amdgcn_exp2f(-1.4426950408889634f * a * a);
  float er = fmaf(-poly, e, 1.0f);
  er = copysignf(er, y);
  const float hx = 0.5f * x;
  return fmaf(hx, er, hx);
}

// compile-time plucker pair tables (i<j over 16 dims, row-major upper-tri)
constexpr int PLU_I[PLU] = {
    0, 0, 0, 0, 0, 0, 0, 0, 0, 0, 0, 0, 0, 0, 0,      // 15
    1, 1, 1, 1, 1, 1, 1, 1, 1, 1, 1, 1, 1, 1,          // 14
    2, 2, 2, 2, 2, 2, 2, 2, 2, 2, 2, 2, 2,             // 13
    3, 3, 3, 3, 3, 3, 3, 3, 3, 3, 3, 3,                // 12
    4, 4, 4, 4, 4, 4, 4, 4, 4, 4, 4,                   // 11
    5, 5, 5, 5, 5, 5, 5, 5, 5, 5,                      // 10
    6, 6, 6, 6, 6, 6, 6, 6, 6,                         // 9
    7, 7, 7, 7, 7, 7, 7, 7,                            // 8
    8, 8, 8, 8, 8, 8, 8,                               // 7
    9, 9, 9, 9, 9, 9,                                  // 6
    10, 10, 10, 10, 10,                                // 5
    11, 11, 11, 11,                                    // 4
    12, 12, 12,                                        // 3
    13, 13,                                            // 2
    14};                                               // 1
constexpr int PLU_J[PLU] = {
    1, 2, 3, 4, 5, 6, 7, 8, 9, 10, 11, 12, 13, 14, 15,
    2, 3, 4, 5, 6, 7, 8, 9, 10, 11, 12, 13, 14, 15,
    3, 4, 5, 6, 7, 8, 9, 10, 11, 12, 13, 14, 15,
    4, 5, 6, 7, 8, 9, 10, 11, 12, 13, 14, 15,
    5, 6, 7, 8, 9, 10, 11, 12, 13, 14, 15,
    6, 7, 8, 9, 10, 11, 12, 13, 14, 15,
    7, 8, 9, 10, 11, 12, 13, 14, 15,
    8, 9, 10, 11, 12, 13, 14, 15,
    9, 10, 11, 12, 13, 14, 15,
    10, 11, 12, 13, 14, 15,
    11, 12, 13, 14, 15,
    12, 13, 14, 15,
    13, 14, 15,
    14, 15,
    15};

// ---- K_cvtT: fp32 [K x N] -> bf16 [N x Kp] transpose, zero-pad k in [K,Kp) -
__global__ __launch_bounds__(256) void k_cvtT(const float* __restrict__ src,
                                              u16* __restrict__ dst, int K,
                                              int Kp, int N) {
  __shared__ float t[32][33];
  const int k0 = blockIdx.y * 32, n0 = blockIdx.x * 32;
  const int r = threadIdx.x >> 3, c4 = (threadIdx.x & 7) * 4;
  float4 v = {0.f, 0.f, 0.f, 0.f};
  if (k0 + r < K) v = *(const float4*)(src + (size_t)(k0 + r) * N + n0 + c4);
  t[r][c4] = v.x;
  t[r][c4 + 1] = v.y;
  t[r][c4 + 2] = v.z;
  t[r][c4 + 3] = v.w;
  __syncthreads();
  uint2 o;
  o.x = pack2(t[c4][r], t[c4 + 1][r]);
  o.y = pack2(t[c4 + 2][r], t[c4 + 3][r]);
  *(uint2*)(dst + (size_t)(n0 + r) * Kp + k0 + c4) = o;
}

// -- K1: z = h @ red_w + red_b (N x 16 fp32); also emit h as bf16 (N x 1024) -
__global__ __launch_bounds__(256) void k_reduce(const float* __restrict__ h,
                                                const float* __restrict__ red_w,
                                                const float* __restrict__ red_b,
                                                float* __restrict__ z,
                                                u16* __restrict__ hb) {
  __shared__ alignas(16) u16 hs[16 * D_MODEL];  // 32 KB
  const int tid = threadIdx.x;
  const int t0 = blockIdx.x * 16;

  const float4* src = (const float4*)(h + (size_t)t0 * D_MODEL);
  u32* dst = (u32*)hs;
#pragma unroll
  for (int it = 0; it < (16 * D_MODEL / 4) / 256; ++it) {
    const int idx = tid + it * 256;
    const float4 v = src[idx];
    dst[idx * 2 + 0] = pack2(v.x, v.y);
    dst[idx * 2 + 1] = pack2(v.z, v.w);
  }
  __syncthreads();

  // write back bf16 h
  {
    const uint4* s4 = (const uint4*)hs;
    uint4* d4 = (uint4*)(hb + (size_t)t0 * D_MODEL);
#pragma unroll
    for (int it = 0; it < (16 * D_MODEL / 8) / 256; ++it)
      d4[tid + it * 256] = s4[tid + it * 256];
  }

  const int m = tid >> 4, c = tid & 15;
  const u16* hrow = hs + m * D_MODEL;
  float acc = 0.f;
#pragma unroll 8
  for (int i = 0; i < D_MODEL; i += 2) {
    u32 hv = *(const u32*)(hrow + i);
    float h0 = __uint_as_float(hv << 16);
    float h1 = __uint_as_float(hv & 0xffff0000u);
    acc = fmaf(h0, red_w[i * R_DIM + c], acc);
    acc = fmaf(h1, red_w[(i + 1) * R_DIM + c], acc);
  }
  z[(size_t)(t0 + m) * R_DIM + c] = acc + red_b[c];
}

// ---- K2 (MFMA): plucker -> GEMM1 -> gelu for all 6 deltas -> A_cat bf16 ----
// 512 threads / 8 waves, 64-row tiles, 2 blocks/CU. Conflict-free LDS
// (chunk-XOR c ^ (r&15) on 128-u16 rows); zcr hoisted (delta-invariant).
#define PLUG(G)                                                               \
  _Pragma("unroll") for (int cc = 0; cc < 2; ++cc) {                          \
    u32 ow[4];                                                                \
    _Pragma("unroll") for (int eo = 0; eo < 4; ++eo) {                        \
      float pp[2];                                                            \
      _Pragma("unroll") for (int e2 = 0; e2 < 2; ++e2) {                      \
        const int k = ((G)*2 + cc) * 8 + eo * 2 + e2;                         \
        float p = 0.f;                                                        \
        if (k < PLU) {                                                        \
          p = zp[PLU_I[k]] * zcr[PLU_J[k]] - zp[PLU_J[k]] * zcr[PLU_I[k]];    \
          s = fmaf(p, p, s);                                                  \
        }                                                                     \
        pp[e2] = p;                                                           \
      }                                                                       \
      ow[eo] = pack2(pp[0], pp[1]);                                           \
    }                                                                         \
    *(uint4*)&pb[((((G)*2 + cc) ^ rsw) * 8)] = *(uint4*)ow;                   \
  }

__global__ __launch_bounds__(512) void k_plu(const float* __restrict__ z,
                                             const u16* __restrict__ W1t,
                                             const float* __restrict__ g1b,
                                             u16* __restrict__ A, int t0g) {
  __shared__ alignas(16) float zx[96][17];     // rows tg-32 .. tg+63
  __shared__ alignas(16) u16 W1s[128][128];    // [n][k] swizzled, 32 KB
  __shared__ alignas(16) u16 Pb[64][128];      // [m][k] swizzled, 16 KB
  __shared__ float prt[64][8];
  __shared__ float rno[64];
  __shared__ float b1s[128];

  const int tid = threadIdx.x, lane = tid & 63, w = tid >> 6;
  const int wm = w >> 2, wn = w & 3;
  const int n0 = blockIdx.x * 128;  // 0 or 128 of G_DIM
  const int tl = blockIdx.y * 64;   // local token base
  const int tg = t0g + tl;
  const int l0 = tg & (L_SEQ - 1);
  const int mr = lane & 15;
  const int qlane = lane >> 4;

  if (tid < 128) b1s[tid] = g1b[n0 + tid];
  for (int r = tid; r < 96 * 16; r += 512) {
    const int rr = r >> 4, c = r & 15;
    int t = tg - 32 + rr;
    if (t < 0) t = 0;
    zx[rr][c] = z[(size_t)t * R_DIM + c];
  }
  {
    const uint4* src = (const uint4*)(W1t + (size_t)n0 * 128);
    for (int i = tid; i < 128 * 16; i += 512) {
      const int r = i >> 4, c = i & 15;
      *(uint4*)&W1s[r][(c ^ (r & 15)) * 8] = src[i];
    }
  }
  __syncthreads();  // zx + W1s staged

  // delta-invariant current-row z in registers (row = lane for all waves)
  float zcr[R_DIM];
  {
    const float* zc = zx[32 + lane];
#pragma unroll
    for (int c = 0; c < R_DIM; ++c) zcr[c] = zc[c];
  }

  f32x4 acc[2][2];

#pragma unroll 1
  for (int dd = 0; dd < 6; ++dd) {
    const int delta = 1 << dd;
    if (dd) __syncthreads();  // prior frag reads done before Pb overwrite
    {
      const int row = lane;  // token row within 64-row tile; group = w
      const int rsw = lane & 15;
      const float* zpr = zx[32 + row - delta];
      float zp[R_DIM];
#pragma unroll
      for (int c = 0; c < R_DIM; ++c) zp[c] = zpr[c];
      float s = 0.f;
      u16* pb = &Pb[row][0];
      switch (w) {  // wave-uniform branch, each case fully static-unrolled
        case 0: PLUG(0); break;
        case 1: PLUG(1); break;
        case 2: PLUG(2); break;
        case 3: PLUG(3); break;
        case 4: PLUG(4); break;
        case 5: PLUG(5); break;
        case 6: PLUG(6); break;
        default: PLUG(7); break;
      }
      prt[row][w] = s;
    }
    __syncthreads();
    if (tid < 64) {
      const float s = prt[tid][0] + prt[tid][1] + prt[tid][2] + prt[tid][3] +
                      prt[tid][4] + prt[tid][5] + prt[tid][6] + prt[tid][7];
      rno[tid] = 1.0f / fmaxf(sqrtf(s), 1e-6f);
    }
    __syncthreads();
#pragma unroll
    for (int a = 0; a < 2; ++a)
#pragma unroll
      for (int b = 0; b < 2; ++b) acc[a][b] = (f32x4)(0.f);
#pragma unroll
    for (int k0 = 0; k0 < 128; k0 += 32) {
      const int ci = (k0 >> 3) + qlane;
      short8 af[2], bfr[2];
#pragma unroll
      for (int mi = 0; mi < 2; ++mi) {
        const int r = wm * 32 + mi * 16 + mr;
        af[mi] = *(const short8*)&Pb[r][(ci ^ (r & 15)) * 8];
      }
#pragma unroll
      for (int ni = 0; ni < 2; ++ni) {
        const int r = wn * 32 + ni * 16 + mr;
        bfr[ni] = *(const short8*)&W1s[r][(ci ^ (r & 15)) * 8];
      }
#pragma unroll
      for (int mi = 0; mi < 2; ++mi)
#pragma unroll
        for (int ni = 0; ni < 2; ++ni)
          acc[mi][ni] = __builtin_amdgcn_mfma_f32_16x16x32_bf16(
              af[mi], bfr[ni], acc[mi][ni], 0, 0, 0);
    }
#pragma unroll
    for (int mi = 0; mi < 2; ++mi) {
#pragma unroll
      for (int r = 0; r < 4; ++r) {
        const int rowl = wm * 32 + mi * 16 + qlane * 4 + r;
        const bool ok = (l0 + rowl) >= delta;
        const float rn = rno[rowl];
#pragma unroll
        for (int ni = 0; ni < 2; ++ni) {
          const int colL = wn * 32 + ni * 16 + mr;
          const float x = acc[mi][ni][r] * rn + b1s[colL];
          const float ge = gelu_erf(x);
          A[(size_t)(tl + rowl) * K_CAT + dd * G_DIM + n0 + colL] =
              ok ? f2bf(ge) : (u16)0;
        }
      }
    }
  }
}

// ===== 128x128 single-buffer GEMM engine (m97 structure + swizzle) =========
// 256 thr / 4 waves (2x2 of 64x64), BK=64, ONE 32 KB LDS buffer ->
// 4 blocks/CU (grid 1024 = 4/CU exact): cross-block wave overlap hides the
// full vmcnt(0) drain (m114 mechanism; m97/m103 measured 874-912 TF).
// Swizzle: 16B chunk c of row r lives at chunk (c ^ (r&7)); staged via
// pre-swizzled GLOBAL source + linear LDS dest (rule #21), read with XOR.
// Loop: COMP(t) -> barrier(readers done) -> STAGE(t+1) -> vmcnt(0) -> barrier.

#define COMP                                                                  \
  {                                                                           \
    _Pragma("unroll") for (int kk = 0; kk < 2; ++kk) {                        \
      short8 af[4], bfr[4];                                                   \
      _Pragma("unroll") for (int mi = 0; mi < 4; ++mi) {                      \
        const int r = wm * 64 + mi * 16 + mr;                                 \
        af[mi] = *(const short8*)&lds[r * 64 +                                \
                                      (((qlane + kk * 4) ^ (r & 7)) << 3)];   \
      }                                                                       \
      _Pragma("unroll") for (int ni = 0; ni < 4; ++ni) {                      \
        const int r = wn * 64 + ni * 16 + mr;                                 \
        bfr[ni] = *(const short8*)&lds[8192 + r * 64 +                        \
                                       (((qlane + kk * 4) ^ (r & 7)) << 3)];  \
      }                                                                       \
      _Pragma("unroll") for (int mi = 0; mi < 4; ++mi)                        \
          _Pragma("unroll") for (int ni = 0; ni < 4; ++ni) acc[mi][ni] =      \
          __builtin_amdgcn_mfma_f32_16x16x32_bf16(af[mi], bfr[ni],            \
                                                  acc[mi][ni], 0, 0, 0);      \
    }                                                                         \
  }

// --- K3: MFMA GEMM  g = (A_cat @ W2_stacked + cnt*b2)/cnt  (ct x 1024 bf16) -
__global__ __launch_bounds__(256, 4) void k_gemm2(const u16* __restrict__ A,
                                                  const u16* __restrict__ W2t,
                                                  const float* __restrict__ g2b,
                                                  u16* __restrict__ g,
                                                  int t0g) {
  __shared__ alignas(16) u16 lds[16384];  // 32 KB -> 4 blocks/CU
  const int tid = threadIdx.x, lane = tid & 63, w = tid >> 6;
  const int wm = w >> 1, wn = w & 1;

  const int cpx = (int)gridDim.x >> 3;
  const int wi = ((int)blockIdx.x & 7) * cpx + ((int)blockIdx.x >> 3);
  const int n0 = (wi & 7) << 7;   // N fastest: A-panel stays L2-hot per XCD
  const int ml = (wi >> 3) << 7;

  const int lr3 = lane >> 3, lc = lane & 7;
  const int koff = (lc ^ lr3) << 3;  // pre-swizzled global k-offset (u16)
  const int rb = w * 32 + lr3;
  const u16* a0 = A + (size_t)(ml + rb) * K_CAT + koff;
  const u16* b0 = W2t + (size_t)(n0 + rb) * G_DIM + koff;

#define STA(T)                                                                \
  _Pragma("unroll") for (int q = 0; q < 4; ++q)                               \
      GLD16(a0 + (size_t)(q * 8) * K_CAT + (T)*64,                            \
            lds + (w * 32 + q * 8) * 64);
#define STB(T)                                                                \
  _Pragma("unroll") for (int q = 0; q < 4; ++q)                               \
      GLD16(b0 + (size_t)(q * 8) * G_DIM + (((T)*64) & (G_DIM - 1)),          \
            lds + 8192 + (w * 32 + q * 8) * 64);

  const int qlane = lane >> 4, mr = lane & 15;

  f32x4 acc[4][4];
#pragma unroll
  for (int a = 0; a < 4; ++a)
#pragma unroll
    for (int b = 0; b < 4; ++b) acc[a][b] = (f32x4)(0.f);

  const int NT = K_CAT / 64;  // 24
  STA(0);
  STB(0);
  VM0;
  BARB;
#pragma unroll 1
  for (int t = 0; t < NT; ++t) {
    COMP;
    if (t + 1 < NT) {
      BARB;  // all waves' frag reads issued-and-consumed (lgkm drained by MFMA)
      STA(t + 1);
      STB(t + 1);
      VM0;
      BARB;
    }
  }

  const int colb = n0 + wn * 64 + mr;
#pragma unroll
  for (int mi = 0; mi < 4; ++mi) {
#pragma unroll
    for (int r = 0; r < 4; ++r) {
      const int rowl = ml + wm * 64 + mi * 16 + qlane * 4 + r;
      const int l = (t0g + rowl) & (L_SEQ - 1);
      const float cnt = (float)((l >= 1) + (l >= 2) + (l >= 4) + (l >= 8) +
                                (l >= 16) + (l >= 32));
      const float inv = 1.0f / fmaxf(cnt, 1.0f);
#pragma unroll
      for (int ni = 0; ni < 4; ++ni) {
        const int col = colb + ni * 16;
        const float v = (acc[mi][ni][r] + cnt * g2b[col]) * inv;
        g[(size_t)rowl * D_MODEL + col] = f2bf(v);
      }
    }
  }
#undef STA
#undef STB
}

// --- K4: MFMA gate: alpha=sigmoid([hb,g]@gate_w+b); out = a*h + (1-a)*g -----
__global__ __launch_bounds__(256, 4) void k_gate(const u16* __restrict__ hb,
                                                 const u16* __restrict__ g,
                                                 const u16* __restrict__ WtG,
                                                 const float* __restrict__ gb,
                                                 float* __restrict__ out,
                                                 int t0g) {
  __shared__ alignas(16) u16 lds[16384];  // 32 KB -> 4 blocks/CU
  const int tid = threadIdx.x, lane = tid & 63, w = tid >> 6;
  const int wm = w >> 1, wn = w & 1;

  const int cpx = (int)gridDim.x >> 3;
  const int wi = ((int)blockIdx.x & 7) * cpx + ((int)blockIdx.x >> 3);
  const int n0 = (wi & 7) << 7;
  const int ml = (wi >> 3) << 7;

  const int lr3 = lane >> 3, lc = lane & 7;
  const int koff = (lc ^ lr3) << 3;
  const int rb = w * 32 + lr3;
  const u16* ph = hb + (size_t)(t0g + ml + rb) * D_MODEL + koff;
  const u16* pg = g + (size_t)(ml + rb) * D_MODEL + koff;
  const u16* pb = WtG + (size_t)(n0 + rb) * K_GATE + koff;

#define STA(T)                                                                \
  {                                                                           \
    const u16* s_ = ((T) < 16 ? ph : pg) + (size_t)((T)&15) * 64;             \
    _Pragma("unroll") for (int q = 0; q < 4; ++q)                             \
        GLD16(s_ + (size_t)(q * 8) * D_MODEL,                                 \
              lds + (w * 32 + q * 8) * 64);                                   \
  }
#define STB(T)                                                                \
  _Pragma("unroll") for (int q = 0; q < 4; ++q)                               \
      GLD16(pb + (size_t)(q * 8) * K_GATE + (T)*64,                           \
            lds + 8192 + (w * 32 + q * 8) * 64);

  const int qlane = lane >> 4, mr = lane & 15;

  f32x4 acc[4][4];
#pragma unroll
  for (int a = 0; a < 4; ++a)
#pragma unroll
    for (int b = 0; b < 4; ++b) acc[a][b] = (f32x4)(0.f);

  const int NT = K_GATE / 64;  // 32
  STA(0);
  STB(0);
  VM0;
  BARB;
#pragma unroll 1
  for (int t = 0; t < NT; ++t) {
    COMP;
    if (t + 1 < NT) {
      BARB;
      STA(t + 1);
      STB(t + 1);
      VM0;
      BARB;
    }
  }

  const int colb = n0 + wn * 64 + mr;
#pragma unroll
  for (int mi = 0; mi < 4; ++mi) {
#pragma unroll
    for (int r = 0; r < 4; ++r) {
      const int rowl = ml + wm * 64 + mi * 16 + qlane * 4 + r;
      const size_t rowg = (size_t)(t0g + rowl) * D_MODEL;
#pragma unroll
      for (int ni = 0; ni < 4; ++ni) {
        const int col = colb + ni * 16;
        const float x = acc[mi][ni][r] + gb[col];
        const float al = 1.0f / (1.0f + expf(-x));
        const float hv = bf2f(hb[rowg + col]);
        const float gv = bf2f(g[(size_t)rowl * D_MODEL + col]);
        out[rowg + col] = fmaf(al, hv - gv, gv);
      }
    }
  }
#undef STA
#undef STB
}

// ---------------------------- launch ---------------------------------------
extern "C" void kernel_launch(void* const* d_in, const int* in_sizes, int n_in,
                              void* d_out, int out_size, void* d_ws,
                              size_t ws_size, hipStream_t stream) {
  const float* h = (const float*)d_in[0];
  const float* red_w = (const float*)d_in[1];
  const float* red_b = (const float*)d_in[2];
  const float* g1w = (const float*)d_in[3];
  const float* g1b = (const float*)d_in[4];
  const float* g2w = (const float*)d_in[5];
  const float* g2b = (const float*)d_in[6];
  const float* gate_w = (const float*)d_in[7];
  const float* gate_b = (const float*)d_in[8];
  float* out = (float*)d_out;

  const size_t sz_z = ((size_t)N_TOK * R_DIM * 4 + 255) & ~(size_t)255;
  const size_t sz_hb = (size_t)N_TOK * D_MODEL * 2;
  const size_t sz_WtG = (size_t)D_MODEL * K_GATE * 2;
  const size_t sz_W2t = (size_t)D_MODEL * G_DIM * 2;
  const size_t sz_W1t = (size_t)G_DIM * 128 * 2;
  const size_t fixed = sz_z + sz_hb + sz_WtG + sz_W2t + sz_W1t + 4096;

  int nc = 1;
  for (; nc <= 8; nc *= 2) {
    const size_t ct = N_TOK / nc;
    if (fixed + ct * (size_t)K_CAT * 2 + ct * (size_t)D_MODEL * 2 <= ws_size)
      break;
  }
  if (nc > 8) nc = 8;
  const int ct = N_TOK / nc;

  char* p = (char*)d_ws;
  float* z = (float*)p;
  p += sz_z;
  u16* hb = (u16*)p;
  p += sz_hb;
  u16* WtG = (u16*)p;
  p += sz_WtG;
  u16* W2t = (u16*)p;
  p += sz_W2t;
  u16* W1t = (u16*)p;
  p += sz_W1t;
  u16* Abuf = (u16*)p;
  p += (size_t)ct * K_CAT * 2;
  u16* gbuf = (u16*)p;

  k_reduce<<<dim3(N_TOK / 16), 256, 0, stream>>>(h, red_w, red_b, z, hb);
  k_cvtT<<<dim3(G_DIM / 32, 128 / 32), 256, 0, stream>>>(g1w, W1t, PLU, 128,
                                                         G_DIM);
  k_cvtT<<<dim3(D_MODEL / 32, G_DIM / 32), 256, 0, stream>>>(g2w, W2t, G_DIM,
                                                             G_DIM, D_MODEL);
  k_cvtT<<<dim3(D_MODEL / 32, K_GATE / 32), 256, 0, stream>>>(
      gate_w, WtG, K_GATE, K_GATE, D_MODEL);

  for (int c = 0; c < nc; ++c) {
    const int t0g = c * ct;
    k_plu<<<dim3(2, ct / 64), 512, 0, stream>>>(z, W1t, g1b, Abuf, t0g);
    k_gemm2<<<dim3((ct / 128) * 8), 256, 0, stream>>>(Abuf, W2t, g2b, gbuf,
                                                      t0g);
    k_gate<<<dim3((ct / 128) * 8), 256, 0, stream>>>(hb, gbuf, WtG, gate_b,
                                                     out, t0g);
  }
}

// Round 10
// 315.119 us; speedup vs baseline: 1.0766x; 1.0766x over previous
//
#include <hip/hip_runtime.h>
#include <hip/hip_bf16.h>
#include <math.h>

typedef unsigned short u16;
typedef unsigned int u32;
typedef __attribute__((ext_vector_type(8))) short short8;
typedef __attribute__((ext_vector_type(4))) float f32x4;

#define L_SEQ 4096
#define N_TOK 16384
#define D_MODEL 1024
#define R_DIM 16
#define PLU 120
#define G_DIM 256
#define K_GATE 2048

typedef __attribute__((address_space(1))) const void* as1cvp;
typedef __attribute__((address_space(3))) void* as3vp;
// async global->LDS, 16B per lane; LDS dest is wave-uniform base + lane*16
#define GLD16(g, l) \
  __builtin_amdgcn_global_load_lds((as1cvp)(g), (as3vp)(l), 16, 0, 0)

#define CFENCE asm volatile("" ::: "memory")
#define BARB                        \
  {                                 \
    CFENCE;                         \
    __builtin_amdgcn_s_barrier();   \
    CFENCE;                         \
  }
#define VM0 asm volatile("s_waitcnt vmcnt(0)" ::: "memory")

__device__ __forceinline__ u16 f2bf(float f) {
  u32 x = __float_as_uint(f);
  u32 lsb = (x >> 16) & 1u;
  x += 0x7fffu + lsb;
  return (u16)(x >> 16);
}
__device__ __forceinline__ float bf2f(u16 u) {
  return __uint_as_float(((u32)u) << 16);
}
__device__ __forceinline__ u32 pack2(float a, float b) {
  return (u32)f2bf(a) | ((u32)f2bf(b) << 16);
}

// exact-GELU via A&S 7.1.26 erf (|eps|<=1.5e-7): ~16 VALU vs libm erff ~35.
__device__ __forceinline__ float gelu_erf(float x) {
  const float y = x * 0.70710678118654752f;
  const float a = fabsf(y);
  const float t = __builtin_amdgcn_rcpf(fmaf(0.3275911f, a, 1.0f));
  float poly = fmaf(1.061405429f, t, -1.453152027f);
  poly = fmaf(poly, t, 1.421413741f);
  poly = fmaf(poly, t, -0.284496736f);
  poly = fmaf(poly, t, 0.254829592f);
  poly *= t;
  const float e = __builtin_amdgcn_exp2f(-1.4426950408889634f * a * a);
  float er = fmaf(-poly, e, 1.0f);
  er = copysignf(er, y);
  const float hx = 0.5f * x;
  return fmaf(hx, er, hx);
}

// compile-time plucker pair tables (i<j over 16 dims, row-major upper-tri)
constexpr int PLU_I[PLU] = {
    0, 0, 0, 0, 0, 0, 0, 0, 0, 0, 0, 0, 0, 0, 0,      // 15
    1, 1, 1, 1, 1, 1, 1, 1, 1, 1, 1, 1, 1, 1,          // 14
    2, 2, 2, 2, 2, 2, 2, 2, 2, 2, 2, 2, 2,             // 13
    3, 3, 3, 3, 3, 3, 3, 3, 3, 3, 3, 3,                // 12
    4, 4, 4, 4, 4, 4, 4, 4, 4, 4, 4,                   // 11
    5, 5, 5, 5, 5, 5, 5, 5, 5, 5,                      // 10
    6, 6, 6, 6, 6, 6, 6, 6, 6,                         // 9
    7, 7, 7, 7, 7, 7, 7, 7,                            // 8
    8, 8, 8, 8, 8, 8, 8,                               // 7
    9, 9, 9, 9, 9, 9,                                  // 6
    10, 10, 10, 10, 10,                                // 5
    11, 11, 11, 11,                                    // 4
    12, 12, 12,                                        // 3
    13, 13,                                            // 2
    14};                                               // 1
constexpr int PLU_J[PLU] = {
    1, 2, 3, 4, 5, 6, 7, 8, 9, 10, 11, 12, 13, 14, 15,
    2, 3, 4, 5, 6, 7, 8, 9, 10, 11, 12, 13, 14, 15,
    3, 4, 5, 6, 7, 8, 9, 10, 11, 12, 13, 14, 15,
    4, 5, 6, 7, 8, 9, 10, 11, 12, 13, 14, 15,
    5, 6, 7, 8, 9, 10, 11, 12, 13, 14, 15,
    6, 7, 8, 9, 10, 11, 12, 13, 14, 15,
    7, 8, 9, 10, 11, 12, 13, 14, 15,
    8, 9, 10, 11, 12, 13, 14, 15,
    9, 10, 11, 12, 13, 14, 15,
    10, 11, 12, 13, 14, 15,
    11, 12, 13, 14, 15,
    12, 13, 14, 15,
    13, 14, 15,
    14, 15,
    15};

// ---- K_cvtT: fp32 [K x N] -> bf16 [N x Kp] transpose, zero-pad k in [K,Kp) -
__global__ __launch_bounds__(256) void k_cvtT(const float* __restrict__ src,
                                              u16* __restrict__ dst, int K,
                                              int Kp, int N) {
  __shared__ float t[32][33];
  const int k0 = blockIdx.y * 32, n0 = blockIdx.x * 32;
  const int r = threadIdx.x >> 3, c4 = (threadIdx.x & 7) * 4;
  float4 v = {0.f, 0.f, 0.f, 0.f};
  if (k0 + r < K) v = *(const float4*)(src + (size_t)(k0 + r) * N + n0 + c4);
  t[r][c4] = v.x;
  t[r][c4 + 1] = v.y;
  t[r][c4 + 2] = v.z;
  t[r][c4 + 3] = v.w;
  __syncthreads();
  uint2 o;
  o.x = pack2(t[c4][r], t[c4 + 1][r]);
  o.y = pack2(t[c4 + 2][r], t[c4 + 3][r]);
  *(uint2*)(dst + (size_t)(n0 + r) * Kp + k0 + c4) = o;
}

// -- K1: z = h @ red_w + red_b (N x 16 fp32); also emit h as bf16 (N x 1024) -
__global__ __launch_bounds__(256) void k_reduce(const float* __restrict__ h,
                                                const float* __restrict__ red_w,
                                                const float* __restrict__ red_b,
                                                float* __restrict__ z,
                                                u16* __restrict__ hb) {
  __shared__ alignas(16) u16 hs[16 * D_MODEL];  // 32 KB
  const int tid = threadIdx.x;
  const int t0 = blockIdx.x * 16;

  const float4* src = (const float4*)(h + (size_t)t0 * D_MODEL);
  u32* dst = (u32*)hs;
#pragma unroll
  for (int it = 0; it < (16 * D_MODEL / 4) / 256; ++it) {
    const int idx = tid + it * 256;
    const float4 v = src[idx];
    dst[idx * 2 + 0] = pack2(v.x, v.y);
    dst[idx * 2 + 1] = pack2(v.z, v.w);
  }
  __syncthreads();

  // write back bf16 h
  {
    const uint4* s4 = (const uint4*)hs;
    uint4* d4 = (uint4*)(hb + (size_t)t0 * D_MODEL);
#pragma unroll
    for (int it = 0; it < (16 * D_MODEL / 8) / 256; ++it)
      d4[tid + it * 256] = s4[tid + it * 256];
  }

  const int m = tid >> 4, c = tid & 15;
  const u16* hrow = hs + m * D_MODEL;
  float acc = 0.f;
#pragma unroll 8
  for (int i = 0; i < D_MODEL; i += 2) {
    u32 hv = *(const u32*)(hrow + i);
    float h0 = __uint_as_float(hv << 16);
    float h1 = __uint_as_float(hv & 0xffff0000u);
    acc = fmaf(h0, red_w[i * R_DIM + c], acc);
    acc = fmaf(h1, red_w[(i + 1) * R_DIM + c], acc);
  }
  z[(size_t)(t0 + m) * R_DIM + c] = acc + red_b[c];
}

// ---- K2 (fused MFMA): plucker -> GEMM1 -> gelu -> Sum over deltas -> GEMM2 -
// Key algebra: g = (Sum_dd A_dd) @ g2w + cnt*b2, since W2's k-index wraps
// mod G_DIM (same g2w per delta). So accumulate As = Sum_dd gelu(..)*mask in
// f32 REGISTERS (as_acc[2][4]) and run GEMM2 ONCE with K=256 (6x fewer
// FLOPs than the old k_gemm2), W2 frags read directly from L2 (0.5 MB hot).
// A_cat never touches HBM. 512 thr / 8 waves, 64-row blocks, grid ct/64.
#define PLUG(G)                                                               \
  _Pragma("unroll") for (int cc = 0; cc < 2; ++cc) {                          \
    u32 ow[4];                                                                \
    _Pragma("unroll") for (int eo = 0; eo < 4; ++eo) {                        \
      float pp[2];                                                            \
      _Pragma("unroll") for (int e2 = 0; e2 < 2; ++e2) {                      \
        const int k = ((G)*2 + cc) * 8 + eo * 2 + e2;                         \
        float p = 0.f;                                                        \
        if (k < PLU) {                                                        \
          p = zp[PLU_I[k]] * zcr[PLU_J[k]] - zp[PLU_J[k]] * zcr[PLU_I[k]];    \
          s = fmaf(p, p, s);                                                  \
        }                                                                     \
        pp[e2] = p;                                                           \
      }                                                                       \
      ow[eo] = pack2(pp[0], pp[1]);                                           \
    }                                                                         \
    *(uint4*)&pb[((((G)*2 + cc) ^ rsw) * 8)] = *(uint4*)ow;                   \
  }

__global__ __launch_bounds__(512) void k_plu(const float* __restrict__ z,
                                             const u16* __restrict__ W1t,
                                             const u16* __restrict__ W2t,
                                             const float* __restrict__ g1b,
                                             const float* __restrict__ g2b,
                                             u16* __restrict__ g, int t0g) {
  __shared__ alignas(16) float zx[96][17];   // rows tg-32 .. tg+63 (6.5 KB)
  __shared__ alignas(16) u16 Pb[64][128];    // [m][k] swizzled (16 KB)
  __shared__ alignas(16) u16 Ad[64][256];    // As bf16, swizzled (32 KB)
  __shared__ float prt[64][8];
  __shared__ float rno[64];
  __shared__ float b1s[G_DIM];

  const int tid = threadIdx.x, lane = tid & 63, w = tid >> 6;
  const int wm = w >> 2, wn = w & 3;  // GEMM1: 2x4 waves of 32x64
  const int tl = blockIdx.x * 64;     // local token base
  const int tg = t0g + tl;
  const int l0 = tg & (L_SEQ - 1);
  const int mr = lane & 15;
  const int qlane = lane >> 4;

  if (tid < G_DIM) b1s[tid] = g1b[tid];
  for (int r = tid; r < 96 * 16; r += 512) {
    const int rr = r >> 4, c = r & 15;
    int t = tg - 32 + rr;
    if (t < 0) t = 0;
    zx[rr][c] = z[(size_t)t * R_DIM + c];
  }
  __syncthreads();  // zx staged

  // delta-invariant current-row z in registers (row = lane for all waves)
  float zcr[R_DIM];
  {
    const float* zc = zx[32 + lane];
#pragma unroll
    for (int c = 0; c < R_DIM; ++c) zcr[c] = zc[c];
  }

  // As accumulator: wave tile 32x64 of the 64x256 As
  f32x4 as_acc[2][4];
#pragma unroll
  for (int a = 0; a < 2; ++a)
#pragma unroll
    for (int b = 0; b < 4; ++b) as_acc[a][b] = (f32x4)(0.f);

#pragma unroll 1
  for (int dd = 0; dd < 6; ++dd) {
    const int delta = 1 << dd;
    if (dd) __syncthreads();  // prior frag reads done before Pb overwrite
    {
      const int row = lane;  // token row within 64-row tile; group = w
      const int rsw = lane & 15;
      const float* zpr = zx[32 + row - delta];
      float zp[R_DIM];
#pragma unroll
      for (int c = 0; c < R_DIM; ++c) zp[c] = zpr[c];
      float s = 0.f;
      u16* pb = &Pb[row][0];
      switch (w) {  // wave-uniform branch, each case fully static-unrolled
        case 0: PLUG(0); break;
        case 1: PLUG(1); break;
        case 2: PLUG(2); break;
        case 3: PLUG(3); break;
        case 4: PLUG(4); break;
        case 5: PLUG(5); break;
        case 6: PLUG(6); break;
        default: PLUG(7); break;
      }
      prt[row][w] = s;
    }
    __syncthreads();
    if (tid < 64) {
      const float s = prt[tid][0] + prt[tid][1] + prt[tid][2] + prt[tid][3] +
                      prt[tid][4] + prt[tid][5] + prt[tid][6] + prt[tid][7];
      rno[tid] = 1.0f / fmaxf(sqrtf(s), 1e-6f);
    }
    __syncthreads();

    // GEMM1: P(64x128) @ W1t(256x128)^T, wave tile 32x64, acc1[2][2... 2x4]
    f32x4 acc1[2][4];
#pragma unroll
    for (int a = 0; a < 2; ++a)
#pragma unroll
      for (int b = 0; b < 4; ++b) acc1[a][b] = (f32x4)(0.f);
#pragma unroll
    for (int k0 = 0; k0 < 128; k0 += 32) {
      const int ci = (k0 >> 3) + qlane;
      short8 af[2], bfr[4];
#pragma unroll
      for (int mi = 0; mi < 2; ++mi) {
        const int r = wm * 32 + mi * 16 + mr;
        af[mi] = *(const short8*)&Pb[r][(ci ^ (r & 15)) * 8];
      }
#pragma unroll
      for (int ni = 0; ni < 4; ++ni) {
        const int r = wn * 64 + ni * 16 + mr;
        bfr[ni] = *(const short8*)(W1t + (size_t)r * 128 + k0 + qlane * 8);
      }
#pragma unroll
      for (int mi = 0; mi < 2; ++mi)
#pragma unroll
        for (int ni = 0; ni < 4; ++ni)
          acc1[mi][ni] = __builtin_amdgcn_mfma_f32_16x16x32_bf16(
              af[mi], bfr[ni], acc1[mi][ni], 0, 0, 0);
    }
    // gelu + mask, accumulate into As registers
#pragma unroll
    for (int mi = 0; mi < 2; ++mi) {
#pragma unroll
      for (int r = 0; r < 4; ++r) {
        const int rowl = wm * 32 + mi * 16 + qlane * 4 + r;
        const bool ok = (l0 + rowl) >= delta;
        const float rn = rno[rowl];
#pragma unroll
        for (int ni = 0; ni < 4; ++ni) {
          const int colL = wn * 64 + ni * 16 + mr;
          const float x = acc1[mi][ni][r] * rn + b1s[colL];
          const float ge = gelu_erf(x);
          as_acc[mi][ni][r] += ok ? ge : 0.f;
        }
      }
    }
  }

  // write As (bf16) to LDS with chunk-XOR swizzle (c&7)^(r&7)
#pragma unroll
  for (int mi = 0; mi < 2; ++mi) {
#pragma unroll
    for (int r = 0; r < 4; ++r) {
      const int rowl = wm * 32 + mi * 16 + qlane * 4 + r;
#pragma unroll
      for (int ni = 0; ni < 4; ++ni) {
        const int colL = wn * 64 + ni * 16 + mr;
        const int ch = colL >> 3;
        const int swz = (ch & 24) | ((ch & 7) ^ (rowl & 7));
        Ad[rowl][swz * 8 + (colL & 7)] = f2bf(as_acc[mi][ni][r]);
      }
    }
  }
  __syncthreads();

  // GEMM2: As(64x256) @ W2t(1024x256)^T, wave owns 64 x 128 cols (w*128)
  f32x4 acc2[4][8];
#pragma unroll
  for (int a = 0; a < 4; ++a)
#pragma unroll
    for (int b = 0; b < 8; ++b) acc2[a][b] = (f32x4)(0.f);
#pragma unroll
  for (int k0 = 0; k0 < 256; k0 += 32) {
    const int ci = (k0 >> 3) + qlane;
    const int swz = (ci & 24);
    short8 af2[4], bf2[8];
#pragma unroll
    for (int mi = 0; mi < 4; ++mi) {
      const int r = mi * 16 + mr;
      af2[mi] = *(const short8*)&Ad[r][(swz | ((ci & 7) ^ (r & 7))) * 8];
    }
#pragma unroll
    for (int fc = 0; fc < 8; ++fc) {
      const int r = w * 128 + fc * 16 + mr;
      bf2[fc] = *(const short8*)(W2t + (size_t)r * G_DIM + k0 + qlane * 8);
    }
#pragma unroll
    for (int mi = 0; mi < 4; ++mi)
#pragma unroll
      for (int fc = 0; fc < 8; ++fc)
        acc2[mi][fc] = __builtin_amdgcn_mfma_f32_16x16x32_bf16(
            af2[mi], bf2[fc], acc2[mi][fc], 0, 0, 0);
  }

  // epilogue: g = (acc2 + cnt*b2) / cnt, write bf16
#pragma unroll
  for (int mi = 0; mi < 4; ++mi) {
#pragma unroll
    for (int r = 0; r < 4; ++r) {
      const int rowl = mi * 16 + qlane * 4 + r;
      const int l = (tg + rowl) & (L_SEQ - 1);
      const float cnt = (float)((l >= 1) + (l >= 2) + (l >= 4) + (l >= 8) +
                                (l >= 16) + (l >= 32));
      const float inv = 1.0f / fmaxf(cnt, 1.0f);
#pragma unroll
      for (int fc = 0; fc < 8; ++fc) {
        const int col = w * 128 + fc * 16 + mr;
        const float v = (acc2[mi][fc][r] + cnt * g2b[col]) * inv;
        g[(size_t)(tl + rowl) * D_MODEL + col] = f2bf(v);
      }
    }
  }
}

// ===== 128x128 single-buffer GEMM engine (m97 structure + swizzle) =========
#define COMP                                                                  \
  {                                                                           \
    _Pragma("unroll") for (int kk = 0; kk < 2; ++kk) {                        \
      short8 af[4], bfr[4];                                                   \
      _Pragma("unroll") for (int mi = 0; mi < 4; ++mi) {                      \
        const int r = wm * 64 + mi * 16 + mr;                                 \
        af[mi] = *(const short8*)&lds[r * 64 +                                \
                                      (((qlane + kk * 4) ^ (r & 7)) << 3)];   \
      }                                                                       \
      _Pragma("unroll") for (int ni = 0; ni < 4; ++ni) {                      \
        const int r = wn * 64 + ni * 16 + mr;                                 \
        bfr[ni] = *(const short8*)&lds[8192 + r * 64 +                        \
                                       (((qlane + kk * 4) ^ (r & 7)) << 3)];  \
      }                                                                       \
      _Pragma("unroll") for (int mi = 0; mi < 4; ++mi)                        \
          _Pragma("unroll") for (int ni = 0; ni < 4; ++ni) acc[mi][ni] =      \
          __builtin_amdgcn_mfma_f32_16x16x32_bf16(af[mi], bfr[ni],            \
                                                  acc[mi][ni], 0, 0, 0);      \
    }                                                                         \
  }

// --- K4: MFMA gate: alpha=sigmoid([hb,g]@gate_w+b); out = a*h + (1-a)*g -----
__global__ __launch_bounds__(256, 4) void k_gate(const u16* __restrict__ hb,
                                                 const u16* __restrict__ g,
                                                 const u16* __restrict__ WtG,
                                                 const float* __restrict__ gb,
                                                 float* __restrict__ out,
                                                 int t0g) {
  __shared__ alignas(16) u16 lds[16384];  // 32 KB -> 4 blocks/CU
  const int tid = threadIdx.x, lane = tid & 63, w = tid >> 6;
  const int wm = w >> 1, wn = w & 1;

  const int cpx = (int)gridDim.x >> 3;
  const int wi = ((int)blockIdx.x & 7) * cpx + ((int)blockIdx.x >> 3);
  const int n0 = (wi & 7) << 7;
  const int ml = (wi >> 3) << 7;

  const int lr3 = lane >> 3, lc = lane & 7;
  const int koff = (lc ^ lr3) << 3;
  const int rb = w * 32 + lr3;
  const u16* ph = hb + (size_t)(t0g + ml + rb) * D_MODEL + koff;
  const u16* pg = g + (size_t)(ml + rb) * D_MODEL + koff;
  const u16* pb = WtG + (size_t)(n0 + rb) * K_GATE + koff;

#define STA(T)                                                                \
  {                                                                           \
    const u16* s_ = ((T) < 16 ? ph : pg) + (size_t)((T)&15) * 64;             \
    _Pragma("unroll") for (int q = 0; q < 4; ++q)                             \
        GLD16(s_ + (size_t)(q * 8) * D_MODEL,                                 \
              lds + (w * 32 + q * 8) * 64);                                   \
  }
#define STB(T)                                                                \
  _Pragma("unroll") for (int q = 0; q < 4; ++q)                               \
      GLD16(pb + (size_t)(q * 8) * K_GATE + (T)*64,                           \
            lds + 8192 + (w * 32 + q * 8) * 64);

  const int qlane = lane >> 4, mr = lane & 15;

  f32x4 acc[4][4];
#pragma unroll
  for (int a = 0; a < 4; ++a)
#pragma unroll
    for (int b = 0; b < 4; ++b) acc[a][b] = (f32x4)(0.f);

  const int NT = K_GATE / 64;  // 32
  STA(0);
  STB(0);
  VM0;
  BARB;
#pragma unroll 1
  for (int t = 0; t < NT; ++t) {
    COMP;
    if (t + 1 < NT) {
      BARB;
      STA(t + 1);
      STB(t + 1);
      VM0;
      BARB;
    }
  }

  const int colb = n0 + wn * 64 + mr;
#pragma unroll
  for (int mi = 0; mi < 4; ++mi) {
#pragma unroll
    for (int r = 0; r < 4; ++r) {
      const int rowl = ml + wm * 64 + mi * 16 + qlane * 4 + r;
      const size_t rowg = (size_t)(t0g + rowl) * D_MODEL;
#pragma unroll
      for (int ni = 0; ni < 4; ++ni) {
        const int col = colb + ni * 16;
        const float x = acc[mi][ni][r] + gb[col];
        const float al = 1.0f / (1.0f + expf(-x));
        const float hv = bf2f(hb[rowg + col]);
        const float gv = bf2f(g[(size_t)rowl * D_MODEL + col]);
        out[rowg + col] = fmaf(al, hv - gv, gv);
      }
    }
  }
#undef STA
#undef STB
}

// ---------------------------- launch ---------------------------------------
extern "C" void kernel_launch(void* const* d_in, const int* in_sizes, int n_in,
                              void* d_out, int out_size, void* d_ws,
                              size_t ws_size, hipStream_t stream) {
  const float* h = (const float*)d_in[0];
  const float* red_w = (const float*)d_in[1];
  const float* red_b = (const float*)d_in[2];
  const float* g1w = (const float*)d_in[3];
  const float* g1b = (const float*)d_in[4];
  const float* g2w = (const float*)d_in[5];
  const float* g2b = (const float*)d_in[6];
  const float* gate_w = (const float*)d_in[7];
  const float* gate_b = (const float*)d_in[8];
  float* out = (float*)d_out;

  const size_t sz_z = ((size_t)N_TOK * R_DIM * 4 + 255) & ~(size_t)255;
  const size_t sz_hb = (size_t)N_TOK * D_MODEL * 2;
  const size_t sz_WtG = (size_t)D_MODEL * K_GATE * 2;
  const size_t sz_W2t = (size_t)D_MODEL * G_DIM * 2;
  const size_t sz_W1t = (size_t)G_DIM * 128 * 2;
  const size_t fixed = sz_z + sz_hb + sz_WtG + sz_W2t + sz_W1t + 4096;

  int nc = 1;
  for (; nc <= 8; nc *= 2) {
    const size_t ct = N_TOK / nc;
    if (fixed + ct * (size_t)D_MODEL * 2 <= ws_size) break;
  }
  if (nc > 8) nc = 8;
  const int ct = N_TOK / nc;

  char* p = (char*)d_ws;
  float* z = (float*)p;
  p += sz_z;
  u16* hb = (u16*)p;
  p += sz_hb;
  u16* WtG = (u16*)p;
  p += sz_WtG;
  u16* W2t = (u16*)p;
  p += sz_W2t;
  u16* W1t = (u16*)p;
  p += sz_W1t;
  u16* gbuf = (u16*)p;

  k_reduce<<<dim3(N_TOK / 16), 256, 0, stream>>>(h, red_w, red_b, z, hb);
  k_cvtT<<<dim3(G_DIM / 32, 128 / 32), 256, 0, stream>>>(g1w, W1t, PLU, 128,
                                                         G_DIM);
  k_cvtT<<<dim3(D_MODEL / 32, G_DIM / 32), 256, 0, stream>>>(g2w, W2t, G_DIM,
                                                             G_DIM, D_MODEL);
  k_cvtT<<<dim3(D_MODEL / 32, K_GATE / 32), 256, 0, stream>>>(
      gate_w, WtG, K_GATE, K_GATE, D_MODEL);

  for (int c = 0; c < nc; ++c) {
    const int t0g = c * ct;
    k_plu<<<dim3(ct / 64), 512, 0, stream>>>(z, W1t, W2t, g1b, g2b, gbuf,
                                             t0g);
    k_gate<<<dim3((ct / 128) * 8), 256, 0, stream>>>(hb, gbuf, WtG, gate_b,
                                                     out, t0g);
  }
}